// Round 6
// baseline (490.781 us; speedup 1.0000x reference)
//
#include <hip/hip_runtime.h>
#include <hip/hip_fp16.h>

#define SEQ 256
#define NPOS 1024

// ---------------- prep: squash(x) + layernorm(g_i,b_i) -> emb0 [1024][256]
__global__ __launch_bounds__(256) void prep_kernel(
    const float* __restrict__ x, const float* __restrict__ g,
    const float* __restrict__ be, float* __restrict__ emb0) {
  const int pos = blockIdx.x;
  const int t = threadIdx.x;  // 256
  float v = x[(size_t)pos * 256 + t];
  float sn = v * v;
  sn += __shfl_xor(sn, 1); sn += __shfl_xor(sn, 2);
  sn += __shfl_xor(sn, 4); sn += __shfl_xor(sn, 8);
  float e = v * (sn / (1.f + sn)) * rsqrtf(sn + 1e-9f);
  __shared__ float red[2][4];
  float s1 = e, s2 = e * e;
  for (int m = 1; m < 64; m <<= 1) { s1 += __shfl_xor(s1, m); s2 += __shfl_xor(s2, m); }
  if ((t & 63) == 0) { red[0][t >> 6] = s1; red[1][t >> 6] = s2; }
  __syncthreads();
  float tot = 0.f, tot2 = 0.f;
#pragma unroll
  for (int i = 0; i < 4; i++) { tot += red[0][i]; tot2 += red[1][i]; }
  float mean = tot * (1.f / 256.f);
  float var = tot2 * (1.f / 256.f) - mean * mean;
  emb0[(size_t)pos * 256 + t] = g[t] * (e - mean) * rsqrtf(var + 1e-3f) + be[t];
}

// ---------------- einsum: u_hat[p,i,o,d] = sum_l W[i,o,d,l]*we[p,i,l] + B[i,o,d]
// block: (i, pos-subtile of 64); 512 threads = (o,d). PT=64 halves W refetch.
template <int INH, int IN_H, int ESTR>
__global__ __launch_bounds__(512) void einsum_kernel(
    const float* __restrict__ W, const float* __restrict__ Bi,
    const float* __restrict__ emb, __half* __restrict__ u, int pos0) {
  constexpr int PT = 64;
  const int i = blockIdx.x;
  const int pt = blockIdx.y;
  const int t = threadIdx.x;  // 512
  const int w = i / IN_H, h = i % IN_H;
  __shared__ float W_lds[16][512];   // [l][o*16+d]
  __shared__ float we_lds[PT][16];
  const float* Wi = W + (size_t)i * 8192;
#pragma unroll
  for (int j = 0; j < 4; j++) {
    const float4 wv = *(const float4*)(Wi + (size_t)t * 16 + j * 4);
    W_lds[j * 4 + 0][t] = wv.x; W_lds[j * 4 + 1][t] = wv.y;
    W_lds[j * 4 + 2][t] = wv.z; W_lds[j * 4 + 3][t] = wv.w;
  }
#pragma unroll
  for (int j = 0; j < PT * 16 / 512; j++) {
    int idx = t + j * 512;
    int p = idx >> 4, l = idx & 15;
    int pos = pos0 + pt * PT + p;
    int s = pos & 255;
    int sr = s + w - 2;
    float val = 0.f;
    if (sr >= 0 && sr < SEQ) val = emb[(size_t)(pos + (w - 2)) * ESTR + h * 16 + l];
    we_lds[p][l] = val;
  }
  __syncthreads();
  float wr[16];
#pragma unroll
  for (int l = 0; l < 16; l++) wr[l] = W_lds[l][t];
  const float bias = Bi[(size_t)i * 512 + t];
  __half* ub = u + ((size_t)(pt * PT) * INH + i) * 512 + t;
#pragma unroll 4
  for (int p = 0; p < PT; p++) {
    float acc = bias;
#pragma unroll
    for (int l = 0; l < 16; l++) acc += wr[l] * we_lds[p][l];
    ub[(size_t)p * INH * 512] = __float2half(acc);
  }
}

// ---------------- routing: 4 waves per position (256 threads) -> 256-VGPR
// cap, so the register-resident u_hat tile (ROWS=INH/4 uint4 = 160 VGPR max)
// does NOT spill. (Rounds 3-5 failure: 512/1024-thread blocks cap VGPRs at
// 128/64 -> 84-164 MB scratch spill.) u_hat read ONCE; all 3 routing passes
// register-resident; cross-wave s-reduction via 8 KB LDS.
// lane l owns (o=l>>1, d=(l&1)*8..+8) of the 512-element s/v vectors.
template <int INH, bool MASK, bool FINAL>
__global__ __launch_bounds__(256, 2) void route_kernel(
    const __half* __restrict__ u, const float* __restrict__ g,
    const float* __restrict__ be, const float* __restrict__ g_o,
    const float* __restrict__ b_o, float* __restrict__ outp, int pos0) {
  constexpr int ROWS = INH / 4;
  const int w = threadIdx.x >> 6;
  const int l = threadIdx.x & 63;
  const int o = l >> 1;
  const int p = blockIdx.x;
  const int posg = pos0 + p;
  const __half* ug = u + (size_t)p * INH * 512 + l * 8;

  __shared__ float red_s[4][512];

  // load this wave's rows once (ROWS independent dwordx4 loads)
  uint4 ureg[ROWS];
#pragma unroll
  for (int r = 0; r < ROWS; r++)
    ureg[r] = *(const uint4*)(ug + (size_t)(w * ROWS + r) * 512);

#define UNPACK(q, f)                                            \
  {                                                             \
    float2 f0 = __half22float2(*(const __half2*)&(q).x);        \
    float2 f1 = __half22float2(*(const __half2*)&(q).y);        \
    float2 f2 = __half22float2(*(const __half2*)&(q).z);        \
    float2 f3 = __half22float2(*(const __half2*)&(q).w);        \
    f[0] = f0.x; f[1] = f0.y; f[2] = f1.x; f[3] = f1.y;         \
    f[4] = f2.x; f[5] = f2.y; f[6] = f3.x; f[7] = f3.y;         \
  }

  // ---- pass A (iter 1): c is constant -> partial row-sum
  float s8[8];
#pragma unroll
  for (int k = 0; k < 8; k++) s8[k] = 0.f;
#pragma unroll
  for (int r = 0; r < ROWS; r++) {
    float u8[8];
    UNPACK(ureg[r], u8);
#pragma unroll
    for (int k = 0; k < 8; k++) s8[k] += u8[k];
  }
  // cross-wave reduce
  *(float4*)&red_s[w][l * 8]     = make_float4(s8[0], s8[1], s8[2], s8[3]);
  *(float4*)&red_s[w][l * 8 + 4] = make_float4(s8[4], s8[5], s8[6], s8[7]);
  __syncthreads();
#pragma unroll
  for (int k = 0; k < 8; k++) s8[k] = 0.f;
#pragma unroll
  for (int w2 = 0; w2 < 4; w2++) {
    float4 a = *(const float4*)&red_s[w2][l * 8];
    float4 b = *(const float4*)&red_s[w2][l * 8 + 4];
    s8[0] += a.x; s8[1] += a.y; s8[2] += a.z; s8[3] += a.w;
    s8[4] += b.x; s8[5] += b.y; s8[6] += b.z; s8[7] += b.w;
  }
  const float c1 = MASK ? (o == 0 ? 0.f : (1.f / 31.f)) : (1.f / 32.f);
  float vd[8], vout[8];
  {
    float sn = 0.f;
#pragma unroll
    for (int k = 0; k < 8; k++) { s8[k] *= c1; sn += s8[k] * s8[k]; }
    sn += __shfl_xor(sn, 1);
    float f = (sn / (1.f + sn)) * rsqrtf(sn + 1e-9f);
#pragma unroll
    for (int k = 0; k < 8; k++) vd[k] = s8[k] * f;  // vd = v1
  }

  // ---- passes B, C (iters 2, 3). pass C dots against v1+v2 (b telescopes).
#pragma unroll
  for (int iter = 0; iter < 2; iter++) {
    float sacc[8];
#pragma unroll
    for (int k = 0; k < 8; k++) sacc[k] = 0.f;
#pragma unroll
    for (int r = 0; r < ROWS; r++) {
      float u8[8];
      UNPACK(ureg[r], u8);
      float a = u8[0] * vd[0];
#pragma unroll
      for (int k = 1; k < 8; k++) a = fmaf(u8[k], vd[k], a);
      a += __shfl_xor(a, 1);                 // full dot over d=16
      if (MASK && o == 0) a = -1e30f;
      float m = a;
      m = fmaxf(m, __shfl_xor(m, 2)); m = fmaxf(m, __shfl_xor(m, 4));
      m = fmaxf(m, __shfl_xor(m, 8)); m = fmaxf(m, __shfl_xor(m, 16));
      m = fmaxf(m, __shfl_xor(m, 32));
      float e = (MASK && o == 0) ? 0.f : __expf(a - m);
      float ss = e;
      ss += __shfl_xor(ss, 2); ss += __shfl_xor(ss, 4);
      ss += __shfl_xor(ss, 8); ss += __shfl_xor(ss, 16);
      ss += __shfl_xor(ss, 32);
      float c = __fdividef(e, ss);
#pragma unroll
      for (int k = 0; k < 8; k++) sacc[k] = fmaf(c, u8[k], sacc[k]);
    }
    // cross-wave reduce (buffer-reuse guard, then write/read)
    __syncthreads();
    *(float4*)&red_s[w][l * 8]     = make_float4(sacc[0], sacc[1], sacc[2], sacc[3]);
    *(float4*)&red_s[w][l * 8 + 4] = make_float4(sacc[4], sacc[5], sacc[6], sacc[7]);
    __syncthreads();
#pragma unroll
    for (int k = 0; k < 8; k++) sacc[k] = 0.f;
#pragma unroll
    for (int w2 = 0; w2 < 4; w2++) {
      float4 a = *(const float4*)&red_s[w2][l * 8];
      float4 b = *(const float4*)&red_s[w2][l * 8 + 4];
      sacc[0] += a.x; sacc[1] += a.y; sacc[2] += a.z; sacc[3] += a.w;
      sacc[4] += b.x; sacc[5] += b.y; sacc[6] += b.z; sacc[7] += b.w;
    }
    float sn = 0.f;
#pragma unroll
    for (int k = 0; k < 8; k++) sn += sacc[k] * sacc[k];
    sn += __shfl_xor(sn, 1);
    float f = (sn / (1.f + sn)) * rsqrtf(sn + 1e-9f);
#pragma unroll
    for (int k = 0; k < 8; k++) {
      vout[k] = sacc[k] * f;
      vd[k] += vout[k];                      // vd becomes v1+v2 for pass C
    }
  }

  // ---- epilogue (identical in every wave; wave 0 writes): LN over 512
  float s1 = 0.f, s2 = 0.f;
#pragma unroll
  for (int k = 0; k < 8; k++) { s1 += vout[k]; s2 += vout[k] * vout[k]; }
  for (int m = 1; m < 64; m <<= 1) { s1 += __shfl_xor(s1, m); s2 += __shfl_xor(s2, m); }
  float mean = s1 * (1.f / 512.f);
  float var = s2 * (1.f / 512.f) - mean * mean;
  float rstd = rsqrtf(var + 1e-3f);
  const float4 g0 = *(const float4*)(g + 8 * l);
  const float4 g1 = *(const float4*)(g + 8 * l + 4);
  const float4 be0 = *(const float4*)(be + 8 * l);
  const float4 be1 = *(const float4*)(be + 8 * l + 4);
  float nv[8];
  nv[0] = g0.x * (vout[0] - mean) * rstd + be0.x;
  nv[1] = g0.y * (vout[1] - mean) * rstd + be0.y;
  nv[2] = g0.z * (vout[2] - mean) * rstd + be0.z;
  nv[3] = g0.w * (vout[3] - mean) * rstd + be0.w;
  nv[4] = g1.x * (vout[4] - mean) * rstd + be1.x;
  nv[5] = g1.y * (vout[5] - mean) * rstd + be1.y;
  nv[6] = g1.z * (vout[6] - mean) * rstd + be1.z;
  nv[7] = g1.w * (vout[7] - mean) * rstd + be1.w;

  if (!FINAL) {
    if (w == 0) {
      float4 w0 = {nv[0], nv[1], nv[2], nv[3]};
      float4 w1 = {nv[4], nv[5], nv[6], nv[7]};
      float* op = outp + (size_t)posg * 512 + 8 * l;
      *(float4*)op = w0; *(float4*)(op + 4) = w1;
    }
  } else {
    float l2 = 0.f;
#pragma unroll
    for (int k = 0; k < 8; k++) l2 += nv[k] * nv[k];
    l2 += __shfl_xor(l2, 1);
    float len = sqrtf(l2 + 1e-9f);
    float a1 = len, a2 = len * len;
    for (int m = 1; m < 64; m <<= 1) { a1 += __shfl_xor(a1, m); a2 += __shfl_xor(a2, m); }
    float mm = a1 * (1.f / 64.f);            // each o counted twice -> /64
    float vv = a2 * (1.f / 64.f) - mm * mm;
    if (w == 0 && (l & 1) == 0)
      outp[(size_t)posg * 32 + o] = g_o[o] * (len - mm) * rsqrtf(vv + 1e-3f) + b_o[o];
  }
#undef UNPACK
}

extern "C" void kernel_launch(void* const* d_in, const int* in_sizes, int n_in,
                              void* d_out, int out_size, void* d_ws, size_t ws_size,
                              hipStream_t stream) {
  const float* x    = (const float*)d_in[0];
  const float* W0   = (const float*)d_in[1];
  const float* B0   = (const float*)d_in[2];
  const float* W1   = (const float*)d_in[3];
  const float* B1   = (const float*)d_in[4];
  const float* g_i  = (const float*)d_in[5];
  const float* b_i  = (const float*)d_in[6];
  const float* g_m0 = (const float*)d_in[7];
  const float* b_m0 = (const float*)d_in[8];
  const float* g_m1 = (const float*)d_in[9];
  const float* b_m1 = (const float*)d_in[10];
  const float* g_o  = (const float*)d_in[11];
  const float* b_o  = (const float*)d_in[12];
  float* out = (float*)d_out;

  char* ws = (char*)d_ws;
  float* emb0 = (float*)ws;                       // 1 MB
  float* emb1 = (float*)(ws + (1 << 20));         // 2 MB
  __half* ubuf = (__half*)(ws + (4 << 20));       // chunked u_hat

  size_t avail = ws_size > (size_t)(4 << 20) ? ws_size - (size_t)(4 << 20) : 0;
  int chunk = 1024;
  while (chunk > 64 && (size_t)chunk * 163840 > avail) chunk >>= 1;

  prep_kernel<<<NPOS, 256, 0, stream>>>(x, g_i, b_i, emb0);

  for (int p0 = 0; p0 < NPOS; p0 += chunk) {
    int cp = (NPOS - p0 < chunk) ? (NPOS - p0) : chunk;
    einsum_kernel<80, 16, 256><<<dim3(80, cp / 64), 512, 0, stream>>>(W0, B0, emb0, ubuf, p0);
    route_kernel<80, false, false><<<cp, 256, 0, stream>>>(ubuf, g_m0, b_m0, nullptr, nullptr, emb1, p0);
  }
  for (int p0 = 0; p0 < NPOS; p0 += chunk) {
    int cp = (NPOS - p0 < chunk) ? (NPOS - p0) : chunk;
    einsum_kernel<160, 32, 512><<<dim3(160, cp / 64), 512, 0, stream>>>(W1, B1, emb1, ubuf, p0);
    route_kernel<160, true, true><<<cp, 256, 0, stream>>>(ubuf, g_m1, b_m1, g_o, b_o, out, p0);
  }
}

// Round 7
// 271.014 us; speedup vs baseline: 1.8109x; 1.8109x over previous
//
#include <hip/hip_runtime.h>
#include <hip/hip_fp16.h>

#define SEQ 256
#define NPOS 1024

// ---------------- prep: squash(x) + layernorm(g_i,b_i) -> emb0 [1024][256]
__global__ __launch_bounds__(256) void prep_kernel(
    const float* __restrict__ x, const float* __restrict__ g,
    const float* __restrict__ be, float* __restrict__ emb0) {
  const int pos = blockIdx.x;
  const int t = threadIdx.x;  // 256
  float v = x[(size_t)pos * 256 + t];
  float sn = v * v;
  sn += __shfl_xor(sn, 1); sn += __shfl_xor(sn, 2);
  sn += __shfl_xor(sn, 4); sn += __shfl_xor(sn, 8);
  float e = v * (sn / (1.f + sn)) * rsqrtf(sn + 1e-9f);
  __shared__ float red[2][4];
  float s1 = e, s2 = e * e;
  for (int m = 1; m < 64; m <<= 1) { s1 += __shfl_xor(s1, m); s2 += __shfl_xor(s2, m); }
  if ((t & 63) == 0) { red[0][t >> 6] = s1; red[1][t >> 6] = s2; }
  __syncthreads();
  float tot = 0.f, tot2 = 0.f;
#pragma unroll
  for (int i = 0; i < 4; i++) { tot += red[0][i]; tot2 += red[1][i]; }
  float mean = tot * (1.f / 256.f);
  float var = tot2 * (1.f / 256.f) - mean * mean;
  emb0[(size_t)pos * 256 + t] = g[t] * (e - mean) * rsqrtf(var + 1e-3f) + be[t];
}

// ---------------- einsum: u_hat[p,i,o,d] = sum_l W[i,o,d,l]*we[p,i,l] + B[i,o,d]
// block: (i, pos-subtile of 64); 512 threads = (o,d).
template <int INH, int IN_H, int ESTR>
__global__ __launch_bounds__(512) void einsum_kernel(
    const float* __restrict__ W, const float* __restrict__ Bi,
    const float* __restrict__ emb, __half* __restrict__ u, int pos0) {
  constexpr int PT = 64;
  const int i = blockIdx.x;
  const int pt = blockIdx.y;
  const int t = threadIdx.x;  // 512
  const int w = i / IN_H, h = i % IN_H;
  __shared__ float W_lds[16][512];   // [l][o*16+d]
  __shared__ float we_lds[PT][16];
  const float* Wi = W + (size_t)i * 8192;
#pragma unroll
  for (int j = 0; j < 4; j++) {
    const float4 wv = *(const float4*)(Wi + (size_t)t * 16 + j * 4);
    W_lds[j * 4 + 0][t] = wv.x; W_lds[j * 4 + 1][t] = wv.y;
    W_lds[j * 4 + 2][t] = wv.z; W_lds[j * 4 + 3][t] = wv.w;
  }
#pragma unroll
  for (int j = 0; j < PT * 16 / 512; j++) {
    int idx = t + j * 512;
    int p = idx >> 4, l = idx & 15;
    int pos = pos0 + pt * PT + p;
    int s = pos & 255;
    int sr = s + w - 2;
    float val = 0.f;
    if (sr >= 0 && sr < SEQ) val = emb[(size_t)(pos + (w - 2)) * ESTR + h * 16 + l];
    we_lds[p][l] = val;
  }
  __syncthreads();
  float wr[16];
#pragma unroll
  for (int l = 0; l < 16; l++) wr[l] = W_lds[l][t];
  const float bias = Bi[(size_t)i * 512 + t];
  __half* ub = u + ((size_t)(pt * PT) * INH + i) * 512 + t;
#pragma unroll 4
  for (int p = 0; p < PT; p++) {
    float acc = bias;
#pragma unroll
    for (int l = 0; l < 16; l++) acc += wr[l] * we_lds[p][l];
    ub[(size_t)p * INH * 512] = __float2half(acc);
  }
}

// ---------------- routing: one block per position; u_hat staged ONCE into
// LDS (INH*1KB: 160KB layer-1 = full LDS, 80KB layer-0) via async
// global_load_lds (no VGPR round-trip -> no spill; rounds 3-6 failure mode:
// register tiles spill at the 128-VGPR cap). 3 routing passes read LDS.
// Cross-wave s-reduction via 16KB global scratch (L1/L2-resident; LDS is
// fully consumed by u_hat). lane l owns (o=l>>1, d=(l&1)*8..+8).
template <int INH, bool MASK, bool FINAL>
__global__ __launch_bounds__(512, 1) void route_kernel(
    const __half* __restrict__ u, const float* __restrict__ g,
    const float* __restrict__ be, const float* __restrict__ g_o,
    const float* __restrict__ b_o, float* __restrict__ outp,
    float* __restrict__ red, int pos0) {
  constexpr int ROWS = INH / 8;
  const int w = threadIdx.x >> 6;
  const int l = threadIdx.x & 63;
  const int o = l >> 1;
  const int p = blockIdx.x;
  const int posg = pos0 + p;

  __shared__ __half u_lds[INH][512];

  // ---- stage u_hat once: wave w DMAs rows [w*ROWS, (w+1)*ROWS)
  const __half* ug = u + (size_t)p * INH * 512;
#pragma unroll
  for (int r = 0; r < ROWS; r++) {
    const int row = w * ROWS + r;
    __builtin_amdgcn_global_load_lds(
        (const __attribute__((address_space(1))) unsigned int*)(ug + (size_t)row * 512 + l * 8),
        (__attribute__((address_space(3))) unsigned int*)&u_lds[row][0],
        16, 0, 0);
  }
  __syncthreads();  // drains vmcnt -> LDS populated

  float* rp = red + (size_t)p * 4096;  // 8 waves * 512 floats

#define UNPACK(q, f)                                            \
  {                                                             \
    float2 f0 = __half22float2(*(const __half2*)&(q).x);        \
    float2 f1 = __half22float2(*(const __half2*)&(q).y);        \
    float2 f2 = __half22float2(*(const __half2*)&(q).z);        \
    float2 f3 = __half22float2(*(const __half2*)&(q).w);        \
    f[0] = f0.x; f[1] = f0.y; f[2] = f1.x; f[3] = f1.y;         \
    f[4] = f2.x; f[5] = f2.y; f[6] = f3.x; f[7] = f3.y;         \
  }

#define CROSSWAVE_REDUCE(s)                                          \
  {                                                                  \
    *(float4*)(rp + w * 512 + l * 8) = make_float4(s[0], s[1], s[2], s[3]); \
    *(float4*)(rp + w * 512 + l * 8 + 4) = make_float4(s[4], s[5], s[6], s[7]); \
    __syncthreads();                                                 \
    _Pragma("unroll") for (int k = 0; k < 8; k++) s[k] = 0.f;        \
    _Pragma("unroll") for (int w2 = 0; w2 < 8; w2++) {               \
      float4 a = *(const float4*)(rp + w2 * 512 + l * 8);            \
      float4 b = *(const float4*)(rp + w2 * 512 + l * 8 + 4);        \
      s[0] += a.x; s[1] += a.y; s[2] += a.z; s[3] += a.w;            \
      s[4] += b.x; s[5] += b.y; s[6] += b.z; s[7] += b.w;            \
    }                                                                \
    __syncthreads();                                                 \
  }

  // ---- pass A (iter 1): c is constant -> row-sum
  float s8[8];
#pragma unroll
  for (int k = 0; k < 8; k++) s8[k] = 0.f;
  for (int r = 0; r < ROWS; r++) {
    uint4 q = *(const uint4*)&u_lds[w * ROWS + r][l * 8];
    float u8[8];
    UNPACK(q, u8);
#pragma unroll
    for (int k = 0; k < 8; k++) s8[k] += u8[k];
  }
  CROSSWAVE_REDUCE(s8);
  const float c1 = MASK ? (o == 0 ? 0.f : (1.f / 31.f)) : (1.f / 32.f);
  float vd[8], vout[8];
  {
    float sn = 0.f;
#pragma unroll
    for (int k = 0; k < 8; k++) { s8[k] *= c1; sn += s8[k] * s8[k]; }
    sn += __shfl_xor(sn, 1);
    float f = (sn / (1.f + sn)) * rsqrtf(sn + 1e-9f);
#pragma unroll
    for (int k = 0; k < 8; k++) vd[k] = s8[k] * f;  // vd = v1
  }

  // ---- passes B, C (iters 2, 3). pass C dots against v1+v2 (b telescopes).
#pragma unroll
  for (int iter = 0; iter < 2; iter++) {
    float sacc[8];
#pragma unroll
    for (int k = 0; k < 8; k++) sacc[k] = 0.f;
    for (int r = 0; r < ROWS; r++) {
      uint4 q = *(const uint4*)&u_lds[w * ROWS + r][l * 8];
      float u8[8];
      UNPACK(q, u8);
      float a = u8[0] * vd[0];
#pragma unroll
      for (int k = 1; k < 8; k++) a = fmaf(u8[k], vd[k], a);
      a += __shfl_xor(a, 1);                 // full dot over d=16
      if (MASK && o == 0) a = -1e30f;
      float m = a;
      m = fmaxf(m, __shfl_xor(m, 2)); m = fmaxf(m, __shfl_xor(m, 4));
      m = fmaxf(m, __shfl_xor(m, 8)); m = fmaxf(m, __shfl_xor(m, 16));
      m = fmaxf(m, __shfl_xor(m, 32));
      float e = (MASK && o == 0) ? 0.f : __expf(a - m);
      float ss = e;
      ss += __shfl_xor(ss, 2); ss += __shfl_xor(ss, 4);
      ss += __shfl_xor(ss, 8); ss += __shfl_xor(ss, 16);
      ss += __shfl_xor(ss, 32);
      float c = __fdividef(e, ss);
#pragma unroll
      for (int k = 0; k < 8; k++) sacc[k] = fmaf(c, u8[k], sacc[k]);
    }
    CROSSWAVE_REDUCE(sacc);
    float sn = 0.f;
#pragma unroll
    for (int k = 0; k < 8; k++) sn += sacc[k] * sacc[k];
    sn += __shfl_xor(sn, 1);
    float f = (sn / (1.f + sn)) * rsqrtf(sn + 1e-9f);
#pragma unroll
    for (int k = 0; k < 8; k++) {
      vout[k] = sacc[k] * f;
      vd[k] += vout[k];                      // vd becomes v1+v2 for pass C
    }
  }

  // ---- epilogue (identical in every wave; wave 0 writes): LN over 512
  float s1 = 0.f, s2 = 0.f;
#pragma unroll
  for (int k = 0; k < 8; k++) { s1 += vout[k]; s2 += vout[k] * vout[k]; }
  for (int m = 1; m < 64; m <<= 1) { s1 += __shfl_xor(s1, m); s2 += __shfl_xor(s2, m); }
  float mean = s1 * (1.f / 512.f);
  float var = s2 * (1.f / 512.f) - mean * mean;
  float rstd = rsqrtf(var + 1e-3f);
  const float4 g0 = *(const float4*)(g + 8 * l);
  const float4 g1 = *(const float4*)(g + 8 * l + 4);
  const float4 be0 = *(const float4*)(be + 8 * l);
  const float4 be1 = *(const float4*)(be + 8 * l + 4);
  float nv[8];
  nv[0] = g0.x * (vout[0] - mean) * rstd + be0.x;
  nv[1] = g0.y * (vout[1] - mean) * rstd + be0.y;
  nv[2] = g0.z * (vout[2] - mean) * rstd + be0.z;
  nv[3] = g0.w * (vout[3] - mean) * rstd + be0.w;
  nv[4] = g1.x * (vout[4] - mean) * rstd + be1.x;
  nv[5] = g1.y * (vout[5] - mean) * rstd + be1.y;
  nv[6] = g1.z * (vout[6] - mean) * rstd + be1.z;
  nv[7] = g1.w * (vout[7] - mean) * rstd + be1.w;

  if (!FINAL) {
    if (w == 0) {
      float4 w0 = {nv[0], nv[1], nv[2], nv[3]};
      float4 w1 = {nv[4], nv[5], nv[6], nv[7]};
      float* op = outp + (size_t)posg * 512 + 8 * l;
      *(float4*)op = w0; *(float4*)(op + 4) = w1;
    }
  } else {
    float l2 = 0.f;
#pragma unroll
    for (int k = 0; k < 8; k++) l2 += nv[k] * nv[k];
    l2 += __shfl_xor(l2, 1);
    float len = sqrtf(l2 + 1e-9f);
    float a1 = len, a2 = len * len;
    for (int m = 1; m < 64; m <<= 1) { a1 += __shfl_xor(a1, m); a2 += __shfl_xor(a2, m); }
    float mm = a1 * (1.f / 64.f);            // each o counted twice -> /64
    float vv = a2 * (1.f / 64.f) - mm * mm;
    if (w == 0 && (l & 1) == 0)
      outp[(size_t)posg * 32 + o] = g_o[o] * (len - mm) * rsqrtf(vv + 1e-3f) + b_o[o];
  }
#undef UNPACK
#undef CROSSWAVE_REDUCE
}

extern "C" void kernel_launch(void* const* d_in, const int* in_sizes, int n_in,
                              void* d_out, int out_size, void* d_ws, size_t ws_size,
                              hipStream_t stream) {
  const float* x    = (const float*)d_in[0];
  const float* W0   = (const float*)d_in[1];
  const float* B0   = (const float*)d_in[2];
  const float* W1   = (const float*)d_in[3];
  const float* B1   = (const float*)d_in[4];
  const float* g_i  = (const float*)d_in[5];
  const float* b_i  = (const float*)d_in[6];
  const float* g_m0 = (const float*)d_in[7];
  const float* b_m0 = (const float*)d_in[8];
  const float* g_m1 = (const float*)d_in[9];
  const float* b_m1 = (const float*)d_in[10];
  const float* g_o  = (const float*)d_in[11];
  const float* b_o  = (const float*)d_in[12];
  float* out = (float*)d_out;

  char* ws = (char*)d_ws;
  float* emb0 = (float*)ws;                       // 1 MB
  float* emb1 = (float*)(ws + (1 << 20));         // 2 MB

  const size_t base = (size_t)4 << 20;
  int chunk = 1024;  // per position: 16 KB red + 160 KB u_hat
  while (chunk > 64 && base + (size_t)chunk * (16384 + 163840) > ws_size) chunk >>= 1;
  float* red  = (float*)(ws + base);
  __half* ubuf = (__half*)(ws + base + (size_t)chunk * 16384);

  prep_kernel<<<NPOS, 256, 0, stream>>>(x, g_i, b_i, emb0);

  for (int p0 = 0; p0 < NPOS; p0 += chunk) {
    int cp = (NPOS - p0 < chunk) ? (NPOS - p0) : chunk;
    einsum_kernel<80, 16, 256><<<dim3(80, cp / 64), 512, 0, stream>>>(W0, B0, emb0, ubuf, p0);
    route_kernel<80, false, false><<<cp, 512, 0, stream>>>(ubuf, g_m0, b_m0, nullptr, nullptr, emb1, red, p0);
  }
  for (int p0 = 0; p0 < NPOS; p0 += chunk) {
    int cp = (NPOS - p0 < chunk) ? (NPOS - p0) : chunk;
    einsum_kernel<160, 32, 512><<<dim3(160, cp / 64), 512, 0, stream>>>(W1, B1, emb1, ubuf, p0);
    route_kernel<160, true, true><<<cp, 512, 0, stream>>>(ubuf, g_m1, b_m1, g_o, b_o, out, red, p0);
  }
}

// Round 8
// 228.441 us; speedup vs baseline: 2.1484x; 1.1864x over previous
//
#include <hip/hip_runtime.h>
#include <hip/hip_fp16.h>

#define SEQ 256
#define NPOS 1024

// ---------------- prep: squash(x) + layernorm(g_i,b_i) -> emb0 [1024][256]
__global__ __launch_bounds__(256) void prep_kernel(
    const float* __restrict__ x, const float* __restrict__ g,
    const float* __restrict__ be, float* __restrict__ emb0) {
  const int pos = blockIdx.x;
  const int t = threadIdx.x;  // 256
  float v = x[(size_t)pos * 256 + t];
  float sn = v * v;
  sn += __shfl_xor(sn, 1); sn += __shfl_xor(sn, 2);
  sn += __shfl_xor(sn, 4); sn += __shfl_xor(sn, 8);
  float e = v * (sn / (1.f + sn)) * rsqrtf(sn + 1e-9f);
  __shared__ float red[2][4];
  float s1 = e, s2 = e * e;
  for (int m = 1; m < 64; m <<= 1) { s1 += __shfl_xor(s1, m); s2 += __shfl_xor(s2, m); }
  if ((t & 63) == 0) { red[0][t >> 6] = s1; red[1][t >> 6] = s2; }
  __syncthreads();
  float tot = 0.f, tot2 = 0.f;
#pragma unroll
  for (int i = 0; i < 4; i++) { tot += red[0][i]; tot2 += red[1][i]; }
  float mean = tot * (1.f / 256.f);
  float var = tot2 * (1.f / 256.f) - mean * mean;
  emb0[(size_t)pos * 256 + t] = g[t] * (e - mean) * rsqrtf(var + 1e-3f) + be[t];
}

// ---------------- einsum: u_hat[p,i,o,d] = sum_l W[i,o,d,l]*we[p,i,l] + B[i,o,d]
// block: (i, pos-subtile of 64); 512 threads = (o,d).
template <int INH, int IN_H, int ESTR>
__global__ __launch_bounds__(512) void einsum_kernel(
    const float* __restrict__ W, const float* __restrict__ Bi,
    const float* __restrict__ emb, __half* __restrict__ u, int pos0) {
  constexpr int PT = 64;
  const int i = blockIdx.x;
  const int pt = blockIdx.y;
  const int t = threadIdx.x;  // 512
  const int w = i / IN_H, h = i % IN_H;
  __shared__ float W_lds[16][512];   // [l][o*16+d]
  __shared__ float we_lds[PT][16];
  const float* Wi = W + (size_t)i * 8192;
#pragma unroll
  for (int j = 0; j < 4; j++) {
    const float4 wv = *(const float4*)(Wi + (size_t)t * 16 + j * 4);
    W_lds[j * 4 + 0][t] = wv.x; W_lds[j * 4 + 1][t] = wv.y;
    W_lds[j * 4 + 2][t] = wv.z; W_lds[j * 4 + 3][t] = wv.w;
  }
#pragma unroll
  for (int j = 0; j < PT * 16 / 512; j++) {
    int idx = t + j * 512;
    int p = idx >> 4, l = idx & 15;
    int pos = pos0 + pt * PT + p;
    int s = pos & 255;
    int sr = s + w - 2;
    float val = 0.f;
    if (sr >= 0 && sr < SEQ) val = emb[(size_t)(pos + (w - 2)) * ESTR + h * 16 + l];
    we_lds[p][l] = val;
  }
  __syncthreads();
  float wr[16];
#pragma unroll
  for (int l = 0; l < 16; l++) wr[l] = W_lds[l][t];
  const float bias = Bi[(size_t)i * 512 + t];
  __half* ub = u + ((size_t)(pt * PT) * INH + i) * 512 + t;
#pragma unroll 4
  for (int p = 0; p < PT; p++) {
    float acc = bias;
#pragma unroll
    for (int l = 0; l < 16; l++) acc += wr[l] * we_lds[p][l];
    ub[(size_t)p * INH * 512] = __float2half(acc);
  }
}

// ---------------- routing: one block per position, 8 waves; u_hat STREAMED
// from global 3x (u_buf is L3-resident at 168MB < 256MB L3 -> re-reads are
// cheap). No big LDS block (16KB red buffer only -> 10 blocks/CU by LDS),
// no register tile (rounds 3-6: spills at 128-VGPR cap), no full-LDS stage
// (round 7: 160KB -> 1 block/CU -> latency-bound at 2 waves/SIMD). High
// occupancy hides the DS-shuffle/exp chains. lane l owns (o=l>>1,
// d=(l&1)*8..+8) of the 512-element s/v vectors.
template <int INH, bool MASK, bool FINAL>
__global__ __launch_bounds__(512) void route_kernel(
    const __half* __restrict__ u, const float* __restrict__ g,
    const float* __restrict__ be, const float* __restrict__ g_o,
    const float* __restrict__ b_o, float* __restrict__ outp, int pos0) {
  constexpr int ROWS = INH / 8;
  const int w = threadIdx.x >> 6;
  const int l = threadIdx.x & 63;
  const int o = l >> 1;
  const int p = blockIdx.x;
  const int posg = pos0 + p;
  // this wave's row range starts at w*ROWS
  const __half* ug = u + (size_t)p * INH * 512 + (size_t)w * ROWS * 512 + l * 8;

  __shared__ float red_s[8][512];

#define UNPACK(q, f)                                            \
  {                                                             \
    float2 f0 = __half22float2(*(const __half2*)&(q).x);        \
    float2 f1 = __half22float2(*(const __half2*)&(q).y);        \
    float2 f2 = __half22float2(*(const __half2*)&(q).z);        \
    float2 f3 = __half22float2(*(const __half2*)&(q).w);        \
    f[0] = f0.x; f[1] = f0.y; f[2] = f1.x; f[3] = f1.y;         \
    f[4] = f2.x; f[5] = f2.y; f[6] = f3.x; f[7] = f3.y;         \
  }

  // ---- pass A (iter 1): c is constant -> row-sum (streamed)
  float s8[8];
#pragma unroll
  for (int k = 0; k < 8; k++) s8[k] = 0.f;
#pragma unroll 4
  for (int r = 0; r < ROWS; r++) {
    uint4 q = *(const uint4*)(ug + (size_t)r * 512);
    float u8[8];
    UNPACK(q, u8);
#pragma unroll
    for (int k = 0; k < 8; k++) s8[k] += u8[k];
  }
  // cross-wave reduce via LDS
  *(float4*)&red_s[w][l * 8]     = make_float4(s8[0], s8[1], s8[2], s8[3]);
  *(float4*)&red_s[w][l * 8 + 4] = make_float4(s8[4], s8[5], s8[6], s8[7]);
  __syncthreads();
#pragma unroll
  for (int k = 0; k < 8; k++) s8[k] = 0.f;
#pragma unroll
  for (int w2 = 0; w2 < 8; w2++) {
    float4 a = *(const float4*)&red_s[w2][l * 8];
    float4 b = *(const float4*)&red_s[w2][l * 8 + 4];
    s8[0] += a.x; s8[1] += a.y; s8[2] += a.z; s8[3] += a.w;
    s8[4] += b.x; s8[5] += b.y; s8[6] += b.z; s8[7] += b.w;
  }
  const float c1 = MASK ? (o == 0 ? 0.f : (1.f / 31.f)) : (1.f / 32.f);
  float vd[8], vout[8];
  {
    float sn = 0.f;
#pragma unroll
    for (int k = 0; k < 8; k++) { s8[k] *= c1; sn += s8[k] * s8[k]; }
    sn += __shfl_xor(sn, 1);
    float f = (sn / (1.f + sn)) * rsqrtf(sn + 1e-9f);
#pragma unroll
    for (int k = 0; k < 8; k++) vd[k] = s8[k] * f;  // vd = v1
  }

  // ---- passes B, C (iters 2, 3). pass C dots against v1+v2 (b telescopes).
#pragma unroll
  for (int iter = 0; iter < 2; iter++) {
    float sacc[8];
#pragma unroll
    for (int k = 0; k < 8; k++) sacc[k] = 0.f;
#pragma unroll 2
    for (int r = 0; r < ROWS; r++) {
      uint4 q = *(const uint4*)(ug + (size_t)r * 512);
      float u8[8];
      UNPACK(q, u8);
      float a = u8[0] * vd[0];
#pragma unroll
      for (int k = 1; k < 8; k++) a = fmaf(u8[k], vd[k], a);
      a += __shfl_xor(a, 1);                 // full dot over d=16
      if (MASK && o == 0) a = -1e30f;
      float m = a;
      m = fmaxf(m, __shfl_xor(m, 2)); m = fmaxf(m, __shfl_xor(m, 4));
      m = fmaxf(m, __shfl_xor(m, 8)); m = fmaxf(m, __shfl_xor(m, 16));
      m = fmaxf(m, __shfl_xor(m, 32));
      float e = (MASK && o == 0) ? 0.f : __expf(a - m);
      float ss = e;
      ss += __shfl_xor(ss, 2); ss += __shfl_xor(ss, 4);
      ss += __shfl_xor(ss, 8); ss += __shfl_xor(ss, 16);
      ss += __shfl_xor(ss, 32);
      float c = __fdividef(e, ss);
#pragma unroll
      for (int k = 0; k < 8; k++) sacc[k] = fmaf(c, u8[k], sacc[k]);
    }
    // cross-wave reduce (guard, write, sync, read)
    __syncthreads();
    *(float4*)&red_s[w][l * 8]     = make_float4(sacc[0], sacc[1], sacc[2], sacc[3]);
    *(float4*)&red_s[w][l * 8 + 4] = make_float4(sacc[4], sacc[5], sacc[6], sacc[7]);
    __syncthreads();
#pragma unroll
    for (int k = 0; k < 8; k++) sacc[k] = 0.f;
#pragma unroll
    for (int w2 = 0; w2 < 8; w2++) {
      float4 a = *(const float4*)&red_s[w2][l * 8];
      float4 b = *(const float4*)&red_s[w2][l * 8 + 4];
      sacc[0] += a.x; sacc[1] += a.y; sacc[2] += a.z; sacc[3] += a.w;
      sacc[4] += b.x; sacc[5] += b.y; sacc[6] += b.z; sacc[7] += b.w;
    }
    float sn = 0.f;
#pragma unroll
    for (int k = 0; k < 8; k++) sn += sacc[k] * sacc[k];
    sn += __shfl_xor(sn, 1);
    float f = (sn / (1.f + sn)) * rsqrtf(sn + 1e-9f);
#pragma unroll
    for (int k = 0; k < 8; k++) {
      vout[k] = sacc[k] * f;
      vd[k] += vout[k];                      // vd becomes v1+v2 for pass C
    }
  }

  // ---- epilogue (identical in every wave; wave 0 writes): LN over 512
  float s1 = 0.f, s2 = 0.f;
#pragma unroll
  for (int k = 0; k < 8; k++) { s1 += vout[k]; s2 += vout[k] * vout[k]; }
  for (int m = 1; m < 64; m <<= 1) { s1 += __shfl_xor(s1, m); s2 += __shfl_xor(s2, m); }
  float mean = s1 * (1.f / 512.f);
  float var = s2 * (1.f / 512.f) - mean * mean;
  float rstd = rsqrtf(var + 1e-3f);
  const float4 g0 = *(const float4*)(g + 8 * l);
  const float4 g1 = *(const float4*)(g + 8 * l + 4);
  const float4 be0 = *(const float4*)(be + 8 * l);
  const float4 be1 = *(const float4*)(be + 8 * l + 4);
  float nv[8];
  nv[0] = g0.x * (vout[0] - mean) * rstd + be0.x;
  nv[1] = g0.y * (vout[1] - mean) * rstd + be0.y;
  nv[2] = g0.z * (vout[2] - mean) * rstd + be0.z;
  nv[3] = g0.w * (vout[3] - mean) * rstd + be0.w;
  nv[4] = g1.x * (vout[4] - mean) * rstd + be1.x;
  nv[5] = g1.y * (vout[5] - mean) * rstd + be1.y;
  nv[6] = g1.z * (vout[6] - mean) * rstd + be1.z;
  nv[7] = g1.w * (vout[7] - mean) * rstd + be1.w;

  if (!FINAL) {
    if (w == 0) {
      float4 w0 = {nv[0], nv[1], nv[2], nv[3]};
      float4 w1 = {nv[4], nv[5], nv[6], nv[7]};
      float* op = outp + (size_t)posg * 512 + 8 * l;
      *(float4*)op = w0; *(float4*)(op + 4) = w1;
    }
  } else {
    float l2 = 0.f;
#pragma unroll
    for (int k = 0; k < 8; k++) l2 += nv[k] * nv[k];
    l2 += __shfl_xor(l2, 1);
    float len = sqrtf(l2 + 1e-9f);
    float a1 = len, a2 = len * len;
    for (int m = 1; m < 64; m <<= 1) { a1 += __shfl_xor(a1, m); a2 += __shfl_xor(a2, m); }
    float mm = a1 * (1.f / 64.f);            // each o counted twice -> /64
    float vv = a2 * (1.f / 64.f) - mm * mm;
    if (w == 0 && (l & 1) == 0)
      outp[(size_t)posg * 32 + o] = g_o[o] * (len - mm) * rsqrtf(vv + 1e-3f) + b_o[o];
  }
#undef UNPACK
}

extern "C" void kernel_launch(void* const* d_in, const int* in_sizes, int n_in,
                              void* d_out, int out_size, void* d_ws, size_t ws_size,
                              hipStream_t stream) {
  const float* x    = (const float*)d_in[0];
  const float* W0   = (const float*)d_in[1];
  const float* B0   = (const float*)d_in[2];
  const float* W1   = (const float*)d_in[3];
  const float* B1   = (const float*)d_in[4];
  const float* g_i  = (const float*)d_in[5];
  const float* b_i  = (const float*)d_in[6];
  const float* g_m0 = (const float*)d_in[7];
  const float* b_m0 = (const float*)d_in[8];
  const float* g_m1 = (const float*)d_in[9];
  const float* b_m1 = (const float*)d_in[10];
  const float* g_o  = (const float*)d_in[11];
  const float* b_o  = (const float*)d_in[12];
  float* out = (float*)d_out;

  char* ws = (char*)d_ws;
  float* emb0 = (float*)ws;                       // 1 MB
  float* emb1 = (float*)(ws + (1 << 20));         // 2 MB
  __half* ubuf = (__half*)(ws + (4 << 20));       // chunked u_hat

  size_t avail = ws_size > (size_t)(4 << 20) ? ws_size - (size_t)(4 << 20) : 0;
  int chunk = 1024;
  while (chunk > 64 && (size_t)chunk * 163840 > avail) chunk >>= 1;

  prep_kernel<<<NPOS, 256, 0, stream>>>(x, g_i, b_i, emb0);

  for (int p0 = 0; p0 < NPOS; p0 += chunk) {
    int cp = (NPOS - p0 < chunk) ? (NPOS - p0) : chunk;
    einsum_kernel<80, 16, 256><<<dim3(80, cp / 64), 512, 0, stream>>>(W0, B0, emb0, ubuf, p0);
    route_kernel<80, false, false><<<cp, 512, 0, stream>>>(ubuf, g_m0, b_m0, nullptr, nullptr, emb1, p0);
  }
  for (int p0 = 0; p0 < NPOS; p0 += chunk) {
    int cp = (NPOS - p0 < chunk) ? (NPOS - p0) : chunk;
    einsum_kernel<160, 32, 512><<<dim3(160, cp / 64), 512, 0, stream>>>(W1, B1, emb1, ubuf, p0);
    route_kernel<160, true, true><<<cp, 512, 0, stream>>>(ubuf, g_m1, b_m1, g_o, b_o, out, p0);
  }
}